// Round 3
// baseline (282.849 us; speedup 1.0000x reference)
//
#include <hip/hip_runtime.h>

// HexPool: out[r, :] = max_{k<7} x[idx[r,k], :], D=64 fp32, idx < N_OUT.
// R3: DIAGNOSTIC — identical kernel to R2, launched TWICE per call.
// max is idempotent and reads only pristine inputs, so double-launch does the
// same work every call (graph-safe). dur_us(R3) - dur_us(R2) = one warm kernel
// execution, which the top-5 profiler window can't show us (harness fills
// at ~100 us each occupy all five slots).

constexpr int N_OUT = 163842;
constexpr int D = 64;
constexpr int K = 7;
constexpr int ROWS_PER_THREAD = 2;
constexpr int GROUPS = N_OUT / ROWS_PER_THREAD;  // 81921, exact

typedef float v4f __attribute__((ext_vector_type(4)));

__global__ __launch_bounds__(256) void HexPool_kernel(
    const float* __restrict__ x,
    const int* __restrict__ idx,
    float* __restrict__ out)
{
    int tid = blockIdx.x * blockDim.x + threadIdx.x;
    int g   = tid >> 4;              // 16-lane group id -> row pair
    int cg  = (tid & 15) << 2;       // column start (multiple of 4)
    if (g >= GROUPS) return;

    const int r0 = g * ROWS_PER_THREAD;
    const int* ip = idx + (size_t)r0 * K;

    int j[ROWS_PER_THREAD][K];
#pragma unroll
    for (int r = 0; r < ROWS_PER_THREAD; ++r)
#pragma unroll
        for (int k = 0; k < K; ++k)
            j[r][k] = ip[r * K + k];

    v4f v[ROWS_PER_THREAD][K];
#pragma unroll
    for (int r = 0; r < ROWS_PER_THREAD; ++r)
#pragma unroll
        for (int k = 0; k < K; ++k)
            v[r][k] = *reinterpret_cast<const v4f*>(x + (size_t)j[r][k] * D + cg);

#pragma unroll
    for (int r = 0; r < ROWS_PER_THREAD; ++r) {
        v4f m = v[r][0];
#pragma unroll
        for (int k = 1; k < K; ++k) {
            m.x = fmaxf(m.x, v[r][k].x);
            m.y = fmaxf(m.y, v[r][k].y);
            m.z = fmaxf(m.z, v[r][k].z);
            m.w = fmaxf(m.w, v[r][k].w);
        }
        __builtin_nontemporal_store(
            m, reinterpret_cast<v4f*>(out + (size_t)(r0 + r) * D + cg));
    }
}

extern "C" void kernel_launch(void* const* d_in, const int* in_sizes, int n_in,
                              void* d_out, int out_size, void* d_ws, size_t ws_size,
                              hipStream_t stream) {
    const float* x   = (const float*)d_in[0];
    const int*   idx = (const int*)d_in[1];
    float*       out = (float*)d_out;

    const long total_threads = (long)GROUPS * 16;  // 1,310,736
    const int  block = 256;
    const int  grid  = (int)((total_threads + block - 1) / block);  // 5121

    // Launched twice: second run recomputes the identical result (idempotent).
    HexPool_kernel<<<grid, block, 0, stream>>>(x, idx, out);
    HexPool_kernel<<<grid, block, 0, stream>>>(x, idx, out);
}

// Round 4
// 237.235 us; speedup vs baseline: 1.1923x; 1.1923x over previous
//
#include <hip/hip_runtime.h>

// HexPool: out[r, :] = max_{k<7} x[idx[r,k], :], D=64 fp32, idx < N_OUT.
// R4: single launch again (R3 was a double-launch diagnostic: kernel ~45 us of
// the ~237 us total; rest is harness poison/restore). Change vs R2: block-wide
// index staging in LDS — one coalesced idx load per thread instead of 14
// redundant per-lane loads heading every thread's dependency chain.

constexpr int N_OUT = 163842;
constexpr int D = 64;
constexpr int K = 7;
constexpr int ROWS_PER_GROUP = 2;                 // rows per 16-lane group
constexpr int ROWS_PER_BLOCK = (256 / 16) * ROWS_PER_GROUP;  // 32
constexpr int IDX_PER_BLOCK = ROWS_PER_BLOCK * K;            // 224

typedef float v4f __attribute__((ext_vector_type(4)));

__global__ __launch_bounds__(256) void HexPool_kernel(
    const float* __restrict__ x,
    const int* __restrict__ idx,
    float* __restrict__ out)
{
    __shared__ int sidx[IDX_PER_BLOCK];

    const int t = threadIdx.x;
    const int blockRow0 = blockIdx.x * ROWS_PER_BLOCK;

    // Stage this block's 224 indices: one coalesced global load per thread.
    if (t < IDX_PER_BLOCK) {
        const long gofs = (long)blockRow0 * K + t;
        sidx[t] = (gofs < (long)N_OUT * K) ? idx[gofs] : 0;
    }
    __syncthreads();

    const int g    = t >> 4;        // group in block, 0..15
    const int cg   = (t & 15) << 2; // column start (multiple of 4)
    const int lr0  = g * ROWS_PER_GROUP;        // local first row
    const int r0   = blockRow0 + lr0;           // global first row

    // Read 14 indices from LDS (same addr across the 16-lane group: broadcast).
    int j[ROWS_PER_GROUP][K];
#pragma unroll
    for (int r = 0; r < ROWS_PER_GROUP; ++r)
#pragma unroll
        for (int k = 0; k < K; ++k)
            j[r][k] = sidx[(lr0 + r) * K + k];

    // Issue all 14 gathers (OOB rows staged idx=0 -> safe read of x[0]).
    v4f v[ROWS_PER_GROUP][K];
#pragma unroll
    for (int r = 0; r < ROWS_PER_GROUP; ++r)
#pragma unroll
        for (int k = 0; k < K; ++k)
            v[r][k] = *reinterpret_cast<const v4f*>(x + (size_t)j[r][k] * D + cg);

#pragma unroll
    for (int r = 0; r < ROWS_PER_GROUP; ++r) {
        v4f m = v[r][0];
#pragma unroll
        for (int k = 1; k < K; ++k) {
            m.x = fmaxf(m.x, v[r][k].x);
            m.y = fmaxf(m.y, v[r][k].y);
            m.z = fmaxf(m.z, v[r][k].z);
            m.w = fmaxf(m.w, v[r][k].w);
        }
        if (r0 + r < N_OUT) {
            __builtin_nontemporal_store(
                m, reinterpret_cast<v4f*>(out + (size_t)(r0 + r) * D + cg));
        }
    }
}

extern "C" void kernel_launch(void* const* d_in, const int* in_sizes, int n_in,
                              void* d_out, int out_size, void* d_ws, size_t ws_size,
                              hipStream_t stream) {
    const float* x   = (const float*)d_in[0];
    const int*   idx = (const int*)d_in[1];
    float*       out = (float*)d_out;

    const int block = 256;
    const int grid  = (N_OUT + ROWS_PER_BLOCK - 1) / ROWS_PER_BLOCK;  // 5121

    HexPool_kernel<<<grid, block, 0, stream>>>(x, idx, out);
}